// Round 7
// baseline (685.936 us; speedup 1.0000x reference)
//
#include <hip/hip_runtime.h>
#include <cmath>

// Problem constants
#define Bz 4
#define Tt 8192
#define Ee 512
#define Hh 8
#define Cc 256
#define KD 64          // E/H
#define HD 128         // E*VF/H
#define NC 32          // T/C
#define EV 1024        // E*VF
#define Mrows (Bz*Tt)  // 32768

typedef unsigned short u16;
typedef __attribute__((ext_vector_type(4))) float f32x4;
typedef __attribute__((ext_vector_type(8))) short s16x8;

__device__ __forceinline__ u16 f2b(float f) {
    union { float f; unsigned u; } v; v.f = f;
    unsigned r = v.u + 0x7FFFu + ((v.u >> 16) & 1u);
    return (u16)(r >> 16);
}
__device__ __forceinline__ float b2f(u16 u) {
    union { unsigned u; float f; } v; v.u = ((unsigned)u) << 16;
    return v.f;
}
#define MFMA16(a, b, c) __builtin_amdgcn_mfma_f32_16x16x32_bf16((a), (b), (c), 0, 0, 0)

// async global->LDS, 16B per lane; lds dest wave-uniform base + lane*16
__device__ __forceinline__ void glds16(const u16* g, u16* l) {
    __builtin_amdgcn_global_load_lds(
        (const __attribute__((address_space(1))) unsigned int*)g,
        (__attribute__((address_space(3))) unsigned int*)l,
        16, 0, 0);
}

// ---------------------------------------------------------------------------
// FRAGMENT-PACKED LAYOUT: element (row, k) of [rows][K] lives at
//   (row>>4)*(K*16) + (k>>5)*512 + ((k>>3)&3)*128 + (row&15)*8 + (k&7)
// ---------------------------------------------------------------------------
__device__ __forceinline__ size_t fpk(int row, int k, int K) {
    return (size_t)(row >> 4) * (K * 16) + (k >> 5) * 512 + ((k >> 3) & 3) * 128 +
           (row & 15) * 8 + (k & 7);
}

// ---------------------------------------------------------------------------
// cast x (fp32) -> bf16 fragment-packed (rows = B*T, K = 512)
// ---------------------------------------------------------------------------
__global__ __launch_bounds__(256) void cast_x_k(const float* __restrict__ x,
                                                u16* __restrict__ xb) {
    size_t i = ((size_t)blockIdx.x * 256 + threadIdx.x) * 4;
    float4 v = *(const float4*)(x + i);
    int m = (int)(i >> 9), e = (int)(i & 511);
    ushort4 o;
    o.x = f2b(v.x); o.y = f2b(v.y); o.z = f2b(v.z); o.w = f2b(v.w);
    *(ushort4*)(xb + fpk(m, e, 512)) = o;
}

// ---------------------------------------------------------------------------
// cast mask fp32 -> bf16 (linear)
// ---------------------------------------------------------------------------
__global__ __launch_bounds__(256) void cast_mask_k(const float* __restrict__ m,
                                                   u16* __restrict__ mb) {
    size_t i = ((size_t)blockIdx.x * 256 + threadIdx.x) * 4;
    float4 v = *(const float4*)(m + i);
    ushort4 o;
    o.x = f2b(v.x); o.y = f2b(v.y); o.z = f2b(v.z); o.w = f2b(v.w);
    *(ushort4*)(mb + i) = o;
}

// ---------------------------------------------------------------------------
// cast + transpose weights: W[K][N] fp32 -> fragment-packed Wt (rows=N, K)
// ---------------------------------------------------------------------------
__global__ __launch_bounds__(256) void castT_k(const float* __restrict__ W,
                                               u16* __restrict__ Wt,
                                               int K, int N, float scale) {
    __shared__ float tile[32][33];
    int k0 = blockIdx.y * 32, n0 = blockIdx.x * 32;
    int r = threadIdx.x >> 3, c4 = (threadIdx.x & 7) * 4;
    float4 v = *(const float4*)(W + (size_t)(k0 + r) * N + n0 + c4);
    tile[r][c4] = v.x; tile[r][c4 + 1] = v.y; tile[r][c4 + 2] = v.z; tile[r][c4 + 3] = v.w;
    __syncthreads();
    ushort4 o;
    o.x = f2b(tile[c4 + 0][r] * scale);
    o.y = f2b(tile[c4 + 1][r] * scale);
    o.z = f2b(tile[c4 + 2][r] * scale);
    o.w = f2b(tile[c4 + 3][r] * scale);
    *(ushort4*)(Wt + fpk(n0 + r, k0 + c4, K)) = o;
}

// ---------------------------------------------------------------------------
// MFMA GEMM (m97 structure): 128x128 tile, 4 waves, double-buffered LDS,
// global_load_lds staging. Epilogues:
//   EPI=0: rotary + q/k fragment-packed per (b,h)
//   EPI=1: Vt fragment-packed per (b,h,n)
//   EPI=3: plain fp32 row-major
//   EPI=4: FUSED per-head RMS(att) + SiLU(g) gate -> fragment-packed gbuf.
//          Block tile covers full head (128 e) x 128 rows; per-row ssq via
//          LDS staging + 16-lane shfl.  att param = ATT buffer.
// ---------------------------------------------------------------------------
template <int EPI>
__global__ __launch_bounds__(256) void gemm_mfma(const u16* __restrict__ A,
                                                 const u16* __restrict__ Bt,
                                                 void* __restrict__ Cout,
                                                 int K, int N,
                                                 const float* __restrict__ sn,
                                                 const float* __restrict__ cs,
                                                 const u16* __restrict__ att) {
    __shared__ __align__(16) u16 pool[20480];   // mainloop 2x8192 dbuf; epi reuse
    u16 (*lds)[8192] = (u16(*)[8192])pool;
    int tid = threadIdx.x;
    int lane = tid & 63, wid = tid >> 6;
    int cL = lane & 15, quad = lane >> 4;
    int M0 = blockIdx.y * 8, N0 = blockIdx.x * 8;   // 16-row tile indices
    int m0 = blockIdx.y * 128 + (wid & 1) * 64;
    int n0 = blockIdx.x * 128 + (wid >> 1) * 64;
    const int KT = K * 16;
    const int NK = K >> 5;

#define STAGE(buf, kc) do {                                                        \
        size_t kofs = (size_t)(kc) * 512 + lane * 8;                               \
        glds16(A  + (size_t)(M0 + wid * 2    ) * KT + kofs,                        \
               &lds[buf][(wid * 2    ) * 512]);                                    \
        glds16(A  + (size_t)(M0 + wid * 2 + 1) * KT + kofs,                        \
               &lds[buf][(wid * 2 + 1) * 512]);                                    \
        glds16(Bt + (size_t)(N0 + wid * 2    ) * KT + kofs,                        \
               &lds[buf][4096 + (wid * 2    ) * 512]);                             \
        glds16(Bt + (size_t)(N0 + wid * 2 + 1) * KT + kofs,                        \
               &lds[buf][4096 + (wid * 2 + 1) * 512]);                             \
    } while (0)

    STAGE(0, 0);
    __syncthreads();

    f32x4 acc[4][4] = {};
    int mh = (wid & 1) * 4, nh = (wid >> 1) * 4;
    for (int kc = 0; kc < NK; ++kc) {
        int cur = kc & 1;
        if (kc + 1 < NK) STAGE(cur ^ 1, kc + 1);
        s16x8 af[4], bfr[4];
        int fo = quad * 128 + cL * 8;
        #pragma unroll
        for (int mt = 0; mt < 4; ++mt)
            af[mt] = *(const s16x8*)(&lds[cur][(mh + mt) * 512 + fo]);
        #pragma unroll
        for (int nt = 0; nt < 4; ++nt)
            bfr[nt] = *(const s16x8*)(&lds[cur][4096 + (nh + nt) * 512 + fo]);
        #pragma unroll
        for (int mt = 0; mt < 4; ++mt)
            #pragma unroll
            for (int nt = 0; nt < 4; ++nt)
                acc[mt][nt] = MFMA16(af[mt], bfr[nt], acc[mt][nt]);
        __syncthreads();
    }
#undef STAGE
    u16* ep = pool + wid * 5120;    // wave-private [64 rows][80] (EPI 0)

    if (EPI == 0) {
        u16* dst = (u16*)Cout;
        int b = m0 >> 13, h = n0 >> 6, tb = m0 & 8191;
        #pragma unroll
        for (int mt = 0; mt < 4; ++mt)
            #pragma unroll
            for (int nt = 0; nt < 4; ++nt)
                #pragma unroll
                for (int i = 0; i < 4; ++i) {
                    int mrow = mt * 16 + quad * 4 + i;
                    int n = n0 + nt * 16 + cL;
                    float v = acc[mt][nt][i];
                    float p = __shfl_xor(v, 1, 64);
                    int t = tb + mrow, kd = n & 63;
                    float c1 = cs[t * 64 + kd], s1 = sn[t * 64 + kd];
                    float o = (n & 1) ? (v * c1 + p * s1) : (v * c1 - p * s1);
                    ep[mrow * 80 + nt * 16 + cL] = f2b(o);
                }
        u16* dstbh = dst + (size_t)(b * 8 + h) * 524288;
        #pragma unroll
        for (int g2 = 0; g2 < 4; ++g2)
            #pragma unroll
            for (int pass = 0; pass < 2; ++pass) {
                int kcol = pass * 32 + quad * 8;
                s16x8 vv = *(const s16x8*)(ep + (g2 * 16 + cL) * 80 + kcol);
                *(s16x8*)(dstbh + fpk(tb + g2 * 16 + cL, kcol, 64)) = vv;
            }
    } else if (EPI == 1) {
        u16* vt = (u16*)Cout;
        #pragma unroll
        for (int mt = 0; mt < 4; ++mt)
            #pragma unroll
            for (int nt = 0; nt < 4; ++nt) {
                int m = m0 + mt * 16 + quad * 4;
                int n = n0 + nt * 16 + cL;
                int b = m >> 13, t = m & 8191;
                int nn = t >> 8, ccc = t & 255;
                int h = n >> 7, e = n & 127;
                ushort4 pk;
                pk.x = f2b(acc[mt][nt][0]);
                pk.y = f2b(acc[mt][nt][1]);
                pk.z = f2b(acc[mt][nt][2]);
                pk.w = f2b(acc[mt][nt][3]);
                *(ushort4*)(vt + (((size_t)((b * 8 + h) * 32 + nn)) << 15) +
                            fpk(e, ccc, 256)) = pk;
            }
    } else if (EPI == 4) {
        // fused RMS + SiLU gate.  Block = rows mb0..+127, head h (full 128 e).
        u16* dst = (u16*)Cout;
        int mb0 = blockIdx.y * 128;
        int h = blockIdx.x;            // n0>>7
        u16* eps = pool;               // [64][138] staged g (bf16)
        int rl = lane >> 4, c16 = lane & 15;
        #pragma unroll
        for (int ph = 0; ph < 2; ++ph) {
            __syncthreads();
            if ((wid & 1) == ph) {
                #pragma unroll
                for (int mt = 0; mt < 4; ++mt)
                    #pragma unroll
                    for (int nt = 0; nt < 4; ++nt)
                        #pragma unroll
                        for (int i = 0; i < 4; ++i)
                            eps[(mt * 16 + quad * 4 + i) * 138 +
                                (wid >> 1) * 64 + nt * 16 + cL] = f2b(acc[mt][nt][i]);
            }
            __syncthreads();
            #pragma unroll
            for (int it = 0; it < 4; ++it) {
                int row = wid * 16 + it * 4 + rl;            // 0..63
                int grow = mb0 + ph * 64 + row;
                size_t arow = (size_t)grow * 1024 + h * 128 + c16 * 8;
                s16x8 av = *(const s16x8*)(att + arow);
                s16x8 gv = *(const s16x8*)(eps + row * 138 + c16 * 8);
                float afv[8], gfv[8];
                float ssq = 0.f;
                #pragma unroll
                for (int j = 0; j < 8; ++j) {
                    afv[j] = b2f((u16)av[j]);
                    gfv[j] = b2f((u16)gv[j]);
                    ssq += afv[j] * afv[j];
                }
                ssq += __shfl_xor(ssq, 1, 16);
                ssq += __shfl_xor(ssq, 2, 16);
                ssq += __shfl_xor(ssq, 4, 16);
                ssq += __shfl_xor(ssq, 8, 16);
                float rms = rsqrtf(ssq * (1.f / 128.f) + 1e-6f);
                s16x8 ov;
                #pragma unroll
                for (int j = 0; j < 8; ++j) {
                    float sg = gfv[j] / (1.f + __expf(-gfv[j]));
                    ov[j] = (short)f2b(sg * afv[j] * rms);
                }
                *(s16x8*)(dst + fpk(grow, h * 128 + c16 * 8, N)) = ov;
            }
        }
    } else {
        float* dst = (float*)Cout;
        #pragma unroll
        for (int mt = 0; mt < 4; ++mt)
            #pragma unroll
            for (int nt = 0; nt < 4; ++nt)
                #pragma unroll
                for (int i = 0; i < 4; ++i)
                    dst[(size_t)(m0 + mt * 16 + quad * 4 + i) * N + n0 + nt * 16 + cL] =
                        acc[mt][nt][i];
    }
}

// ---------------------------------------------------------------------------
// Inner retention, MFMA.  Block = (b, n, h, rtile of 64 rows), 4 waves.
// mask is bf16 now (half the mask VMEM bytes).
// ---------------------------------------------------------------------------
__global__ __launch_bounds__(256) void attn_mfma(const u16* __restrict__ qr,
                                                 const u16* __restrict__ kr,
                                                 const u16* __restrict__ vt,
                                                 const u16* __restrict__ maskb,
                                                 u16* __restrict__ ATT,
                                                 float* __restrict__ iscale_g) {
    __shared__ __align__(16) u16 Ss[64][264];
    __shared__ float partial[4][64];
    __shared__ float sInvL[64];
    int p = blockIdx.x;
    int g = (p & 7) | ((p >> 5) << 3);
    int rtile = (p >> 3) & 3;
    int h = g & 7; int n = (g >> 3) & 31; int b = g >> 8;
    int tid = threadIdx.x, lane = tid & 63, w = tid >> 6;
    int cL = lane & 15, quad = lane >> 4;

    size_t qf_bh = (size_t)(b * 8 + h) * 524288;
    f32x4 acc[4][4] = {};
    if (w <= rtile) {
        const u16* Qb = qr + qf_bh + (size_t)(n * 16 + rtile * 4) * 1024;
        const u16* Kb = kr + qf_bh + (size_t)(n * 16 + w * 4) * 1024;
        #pragma unroll
        for (int kt = 0; kt < 2; ++kt) {
            s16x8 af[4], bfr[4];
            size_t ko = (size_t)kt * 512 + quad * 128 + cL * 8;
            #pragma unroll
            for (int mt = 0; mt < 4; ++mt)
                af[mt] = *(const s16x8*)(Qb + (size_t)mt * 1024 + ko);
            #pragma unroll
            for (int nt = 0; nt < 4; ++nt)
                bfr[nt] = *(const s16x8*)(Kb + (size_t)nt * 1024 + ko);
            #pragma unroll
            for (int mt = 0; mt < 4; ++mt)
                #pragma unroll
                for (int nt = 0; nt < 4; ++nt)
                    acc[mt][nt] = MFMA16(af[mt], bfr[nt], acc[mt][nt]);
        }
    }
    float rs[4][4] = {};
    if (w <= rtile) {
        const u16* mb = maskb + ((size_t)h << 16);
        #pragma unroll
        for (int mt = 0; mt < 4; ++mt)
            #pragma unroll
            for (int nt = 0; nt < 4; ++nt)
                #pragma unroll
                for (int i = 0; i < 4; ++i) {
                    int r = rtile * 64 + mt * 16 + quad * 4 + i;
                    int d = w * 64 + nt * 16 + cL;
                    float s = acc[mt][nt][i] * b2f(mb[r * 256 + d]);
                    Ss[mt * 16 + quad * 4 + i][w * 64 + nt * 16 + cL] = f2b(s);
                    rs[mt][i] += fabsf(s);
                }
    }
    #pragma unroll
    for (int mt = 0; mt < 4; ++mt)
        #pragma unroll
        for (int i = 0; i < 4; ++i) {
            float v = rs[mt][i];
            v += __shfl_xor(v, 1, 16);
            v += __shfl_xor(v, 2, 16);
            v += __shfl_xor(v, 4, 16);
            v += __shfl_xor(v, 8, 16);
            if (cL == 0) partial[w][mt * 16 + quad * 4 + i] = v;
        }
    __syncthreads();
    if (tid < 64) {
        float tot = partial[0][tid] + partial[1][tid] + partial[2][tid] + partial[3][tid];
        tot = fmaxf(tot, 1.f);
        iscale_g[((size_t)((b * 32 + n) * 8 + h)) * 256 + rtile * 64 + tid] = tot;
        sInvL[tid] = 1.f / tot;
    }
    __syncthreads();

    f32x4 o[8] = {};
    const u16* Vb = vt + (((size_t)((b * 8 + h) * 32 + n)) << 15);
    int kmax = 2 * (rtile + 1);
    for (int kt = 0; kt < kmax; ++kt) {
        s16x8 a = *(const s16x8*)(&Ss[w * 16 + cL][kt * 32 + quad * 8]);
        #pragma unroll
        for (int nt = 0; nt < 8; ++nt) {
            s16x8 bv = *(const s16x8*)(Vb + (size_t)nt * 4096 + kt * 512 +
                                       quad * 128 + cL * 8);
            o[nt] = MFMA16(a, bv, o[nt]);
        }
    }
    #pragma unroll
    for (int nt = 0; nt < 8; ++nt)
        #pragma unroll
        for (int i = 0; i < 4; ++i) {
            int r = quad * 4 + i;
            Ss[w * 16 + r][nt * 16 + cL] = f2b(o[nt][i] * sInvL[w * 16 + r]);
        }
    size_t obase = ((size_t)b * 8192 + n * 256 + rtile * 64) * 1024 + h * 128;
    #pragma unroll
    for (int pass = 0; pass < 4; ++pass) {
        int e = pass * 32 + quad * 8;
        s16x8 vv = *(const s16x8*)(&Ss[w * 16 + cL][e]);
        *(s16x8*)(ATT + obase + (size_t)(w * 16 + cL) * 1024 + e) = vv;
    }
}

// ---------------------------------------------------------------------------
// Chunk kv summary, MFMA: kvT[e][kd] = sum_c (vid[c]*V[c][e]) * K[c][kd].
// ---------------------------------------------------------------------------
__global__ __launch_bounds__(256) void chunkkv_mfma(const u16* __restrict__ kr,
                                                    const u16* __restrict__ vt,
                                                    const float* __restrict__ vid,
                                                    float* __restrict__ kvT) {
    __shared__ u16 KtL[64][264];
    int bid = blockIdx.x;
    int h = bid & 7; bid >>= 3;
    int n = bid & 31; int b = bid >> 5;
    int tid = threadIdx.x, lane = tid & 63, w = tid >> 6;
    int cL = lane & 15, quad = lane >> 4;
    size_t qf_bh = (size_t)(b * 8 + h) * 524288;
    {
        int c = tid;
        const u16* rp = kr + qf_bh + (size_t)(n * 16 + (c >> 4)) * 1024 + (c & 15) * 8;
        #pragma unroll
        for (int u = 0; u < 8; ++u) {
            s16x8 vv = *(const s16x8*)(rp + (u >> 2) * 512 + (u & 3) * 128);
            #pragma unroll
            for (int j = 0; j < 8; ++j) KtL[u * 8 + j][c] = (u16)vv[j];
        }
    }
    __syncthreads();
    const u16* Vb = vt + (((size_t)((b * 8 + h) * 32 + n)) << 15);
    f32x4 acc[2][4] = {};
    for (int kt = 0; kt < 8; ++kt) {
        float vidv[8];
        #pragma unroll
        for (int j = 0; j < 8; ++j) vidv[j] = vid[h * 256 + kt * 32 + quad * 8 + j];
        s16x8 af[2];
        #pragma unroll
        for (int mt = 0; mt < 2; ++mt) {
            s16x8 raw = *(const s16x8*)(Vb + (size_t)(w * 2 + mt) * 4096 +
                                        kt * 512 + quad * 128 + cL * 8);
            #pragma unroll
            for (int j = 0; j < 8; ++j)
                af[mt][j] = (short)f2b(b2f((u16)raw[j]) * vidv[j]);
        }
        #pragma unroll
        for (int nt = 0; nt < 4; ++nt) {
            s16x8 bv = *(const s16x8*)(&KtL[nt * 16 + cL][kt * 32 + quad * 8]);
            #pragma unroll
            for (int mt = 0; mt < 2; ++mt) acc[mt][nt] = MFMA16(af[mt], bv, acc[mt][nt]);
        }
    }
    float* out = kvT + ((size_t)((b * 32 + n) * 8 + h)) * 8192;
    #pragma unroll
    for (int mt = 0; mt < 2; ++mt)
        #pragma unroll
        for (int nt = 0; nt < 4; ++nt)
            #pragma unroll
            for (int i = 0; i < 4; ++i)
                out[(w * 32 + mt * 16 + quad * 4 + i) * 64 + nt * 16 + cL] = acc[mt][nt][i];
}

// ---------------------------------------------------------------------------
// PARALLEL scan with register double-buffer prefetch: load kv_{j+1} while
// FMA-ing kv_j -> hides L2/L3 latency on the dependent chain.
// ---------------------------------------------------------------------------
__global__ __launch_bounds__(256) void scan_par(const float* __restrict__ kvT,
                                                u16* __restrict__ kvrecb,
                                                const float* __restrict__ cdv,
                                                float* __restrict__ cscale) {
    int bid = blockIdx.x;
    int n = bid & 31; bid >>= 5;
    int h = bid & 7; int b = bid >> 3;
    int tid = threadIdx.x, lane = tid & 63, g = tid >> 6;
    float cd = cdv[h];
    float st[32], cur[32], nxt[32];
    #pragma unroll
    for (int i = 0; i < 32; ++i) { st[i] = 0.f; nxt[i] = 0.f; }
    if (n > 0) {
        size_t base0 = ((size_t)((b * 32) * 8 + h)) * 8192;
        #pragma unroll
        for (int i = 0; i < 32; ++i) cur[i] = kvT[base0 + (g + 4 * i) * 64 + lane];
    }
    for (int j = 0; j < n; ++j) {
        if (j + 1 < n) {
            size_t basen = ((size_t)((b * 32 + j + 1) * 8 + h)) * 8192;
            #pragma unroll
            for (int i = 0; i < 32; ++i) nxt[i] = kvT[basen + (g + 4 * i) * 64 + lane];
        }
        #pragma unroll
        for (int i = 0; i < 32; ++i) st[i] = st[i] * cd + cur[i];
        #pragma unroll
        for (int i = 0; i < 32; ++i) cur[i] = nxt[i];
    }
    __shared__ float esum[128];
    __shared__ float sSc;
    #pragma unroll
    for (int i = 0; i < 32; ++i) {
        float s = fabsf(st[i]);
        s += __shfl_xor(s, 1, 64);
        s += __shfl_xor(s, 2, 64);
        s += __shfl_xor(s, 4, 64);
        s += __shfl_xor(s, 8, 64);
        s += __shfl_xor(s, 16, 64);
        s += __shfl_xor(s, 32, 64);
        if (lane == 0) esum[g + 4 * i] = s;
    }
    __syncthreads();
    if (tid < 64) {
        float m1 = fmaxf(esum[tid], esum[tid + 64]);
        m1 = fmaxf(m1, __shfl_xor(m1, 1, 64));
        m1 = fmaxf(m1, __shfl_xor(m1, 2, 64));
        m1 = fmaxf(m1, __shfl_xor(m1, 4, 64));
        m1 = fmaxf(m1, __shfl_xor(m1, 8, 64));
        m1 = fmaxf(m1, __shfl_xor(m1, 16, 64));
        m1 = fmaxf(m1, __shfl_xor(m1, 32, 64));
        if (tid == 0) sSc = fmaxf(m1, 1.f);
    }
    __syncthreads();
    float scale = sSc;
    float inv = 1.f / scale;
    size_t baseN = ((size_t)((b * 32 + n) * 8 + h)) * 8192;
    #pragma unroll
    for (int i = 0; i < 32; ++i) {
        int e = g + 4 * i;
        kvrecb[baseN + ((size_t)(lane >> 3) * 128 + e) * 8 + (lane & 7)] = f2b(st[i] * inv);
    }
    if (tid == 0) cscale[(b * 32 + n) * 8 + h] = scale;
}

// ---------------------------------------------------------------------------
// Cross output + combine, MFMA.  Block = (b,n,h), wave owns 64 chunk rows.
// ---------------------------------------------------------------------------
__global__ __launch_bounds__(256) void cross_mfma(const u16* __restrict__ qr,
                                                  const u16* __restrict__ kvrecb,
                                                  const float* __restrict__ iscale_g,
                                                  const float* __restrict__ cscale_g,
                                                  const float* __restrict__ qid,
                                                  u16* __restrict__ ATT) {
    __shared__ __align__(16) u16 X[4][4608];   // per wave [64 rows][72]
    int bid = blockIdx.x;
    int h = bid & 7; bid >>= 3;
    int n = bid & 31; int b = bid >> 5;
    int tid = threadIdx.x, lane = tid & 63, w = tid >> 6;
    int cL = lane & 15, quad = lane >> 4;
    size_t qf_bh = (size_t)(b * 8 + h) * 524288;
    const u16* Qb = qr + qf_bh + (size_t)(n * 16 + w * 4) * 1024;
    const u16* KVb = kvrecb + ((size_t)((b * 32 + n) * 8 + h)) * 8192;
    s16x8 af[4][2];
    #pragma unroll
    for (int mt = 0; mt < 4; ++mt)
        #pragma unroll
        for (int kt = 0; kt < 2; ++kt)
            af[mt][kt] = *(const s16x8*)(Qb + (size_t)mt * 1024 + kt * 512 +
                                         quad * 128 + cL * 8);
    float csc = cscale_g[(b * 32 + n) * 8 + h];
    size_t ibase = ((size_t)((b * 32 + n) * 8 + h)) * 256 + w * 64;
    size_t obase = ((size_t)(b * 8192 + n * 256 + w * 64)) * 1024 + h * 128;
    #pragma unroll
    for (int hn = 0; hn < 2; ++hn) {
        f32x4 acc[4][4] = {};
        #pragma unroll
        for (int kt = 0; kt < 2; ++kt)
            #pragma unroll
            for (int nt = 0; nt < 4; ++nt) {
                int e = (hn * 4 + nt) * 16 + cL;
                s16x8 bv = *(const s16x8*)(KVb + ((size_t)(kt * 4 + quad) * 128 + e) * 8);
                #pragma unroll
                for (int mt = 0; mt < 4; ++mt)
                    acc[mt][nt] = MFMA16(af[mt][kt], bv, acc[mt][nt]);
            }
        #pragma unroll
        for (int mt = 0; mt < 4; ++mt)
            #pragma unroll
            for (int i = 0; i < 4; ++i) {
                int r = mt * 16 + quad * 4 + i;
                float isc = iscale_g[ibase + r];
                float alls = fmaxf(isc, csc);
                float fC = (csc / alls) * qid[h * 256 + w * 64 + r];
                #pragma unroll
                for (int nt = 0; nt < 4; ++nt)
                    X[w][r * 72 + nt * 16 + cL] = f2b(acc[mt][nt][i] * fC);
            }
        #pragma unroll
        for (int g2 = 0; g2 < 4; ++g2)
            #pragma unroll
            for (int pass = 0; pass < 2; ++pass) {
                int r2 = g2 * 16 + cL;
                float isc2 = iscale_g[ibase + r2];
                float fI2 = isc2 / fmaxf(isc2, csc);
                int e = pass * 32 + quad * 8;
                s16x8 sv = *(const s16x8*)(&X[w][r2 * 72 + e]);
                size_t oi = obase + (size_t)r2 * 1024 + hn * 64 + e;
                s16x8 pv = *(const s16x8*)(ATT + oi);
                s16x8 ov;
                #pragma unroll
                for (int j = 0; j < 8; ++j)
                    ov[j] = (short)f2b(b2f((u16)pv[j]) * fI2 + b2f((u16)sv[j]));
                *(s16x8*)(ATT + oi) = ov;
            }
    }
}

// ---------------------------------------------------------------------------
extern "C" void kernel_launch(void* const* d_in, const int* in_sizes, int n_in,
                              void* d_out, int out_size, void* d_ws, size_t ws_size,
                              hipStream_t stream) {
    const float* x    = (const float*)d_in[0];
    const float* sn   = (const float*)d_in[1];
    const float* cs   = (const float*)d_in[2];
    const float* mask = (const float*)d_in[3];
    const float* cdv  = (const float*)d_in[4];
    const float* qid  = (const float*)d_in[5];
    const float* vid  = (const float*)d_in[6];
    const float* Wq   = (const float*)d_in[7];
    const float* Wk   = (const float*)d_in[8];
    const float* Wv   = (const float*)d_in[9];
    const float* Wg   = (const float*)d_in[10];
    const float* Wo   = (const float*)d_in[11];
    float* out = (float*)d_out;

    char* w = (char*)d_ws;
    u16* qr     = (u16*)w;   w += (size_t)16777216 * 2;
    u16* kr     = (u16*)w;   w += (size_t)16777216 * 2;
    u16* vt     = (u16*)w;   w += (size_t)33554432 * 2;
    u16* xbf    = (u16*)w;   w += (size_t)16777216 * 2;
    u16* wqT    = (u16*)w;   w += (size_t)262144 * 2;
    u16* wkT    = (u16*)w;   w += (size_t)262144 * 2;
    u16* wvT    = (u16*)w;   w += (size_t)524288 * 2;
    u16* wgT    = (u16*)w;   w += (size_t)524288 * 2;
    u16* woT    = (u16*)w;   w += (size_t)524288 * 2;
    float* kvT  = (float*)w; w += (size_t)8388608 * 4;
    u16* kvrecb = (u16*)w;   w += (size_t)8388608 * 2;
    float* iscale = (float*)w; w += (size_t)262144 * 4;
    float* cscale = (float*)w; w += (size_t)1024 * 4;
    u16* maskb  = (u16*)w;   w += (size_t)524288 * 2;   // bf16 mask (H,C,C)

    u16* gbuf = qr;            // 67 MB over dead qr+kr after cross_combine
    u16* ATT  = (u16*)d_out;   // 67 MB bf16 scratch inside the output buffer

    dim3 blk(256);
    cast_x_k<<<dim3(16384), blk, 0, stream>>>(x, xbf);
    cast_mask_k<<<dim3(512), blk, 0, stream>>>(mask, maskb);
    castT_k<<<dim3(16, 16), blk, 0, stream>>>(Wq, wqT, 512, 512, 1.0f);
    castT_k<<<dim3(16, 16), blk, 0, stream>>>(Wk, wkT, 512, 512, 0.125f);
    castT_k<<<dim3(32, 16), blk, 0, stream>>>(Wv, wvT, 512, 1024, 1.0f);
    castT_k<<<dim3(32, 16), blk, 0, stream>>>(Wg, wgT, 512, 1024, 1.0f);
    castT_k<<<dim3(16, 32), blk, 0, stream>>>(Wo, woT, 1024, 512, 1.0f);
    gemm_mfma<0><<<dim3(4, 256), blk, 0, stream>>>(xbf, wqT, qr, 512, 512, sn, cs, nullptr);
    gemm_mfma<0><<<dim3(4, 256), blk, 0, stream>>>(xbf, wkT, kr, 512, 512, sn, cs, nullptr);
    gemm_mfma<1><<<dim3(8, 256), blk, 0, stream>>>(xbf, wvT, vt, 512, 1024, nullptr, nullptr, nullptr);
    attn_mfma<<<dim3(4096), blk, 0, stream>>>(qr, kr, vt, maskb, ATT, iscale);
    chunkkv_mfma<<<dim3(1024), blk, 0, stream>>>(kr, vt, vid, kvT);
    scan_par<<<dim3(1024), blk, 0, stream>>>(kvT, kvrecb, cdv, cscale);
    cross_mfma<<<dim3(1024), blk, 0, stream>>>(qr, kvrecb, iscale, cscale, qid, ATT);
    // fused g-GEMM + RMS + SiLU gate (writes gated gbuf directly)
    gemm_mfma<4><<<dim3(8, 256), blk, 0, stream>>>(xbf, wgT, gbuf, 512, 1024, nullptr, nullptr, ATT);
    gemm_mfma<3><<<dim3(4, 256), blk, 0, stream>>>(gbuf, woT, out, 1024, 512, nullptr, nullptr, nullptr);
}

// Round 8
// 642.653 us; speedup vs baseline: 1.0673x; 1.0673x over previous
//
#include <hip/hip_runtime.h>
#include <hip/hip_bf16.h>
#include <cmath>

// Problem constants
#define Bz 4
#define Tt 8192
#define Ee 512
#define Hh 8
#define Cc 256
#define KD 64          // E/H
#define HD 128         // E*VF/H
#define NC 32          // T/C
#define EV 1024        // E*VF
#define Mrows (Bz*Tt)  // 32768

typedef unsigned short u16;
typedef __attribute__((ext_vector_type(4))) float f32x4;
typedef __attribute__((ext_vector_type(8))) short s16x8;

__device__ __forceinline__ u16 f2b(float f) {
    __hip_bfloat16 h = __float2bfloat16(f);   // RNE, same as manual round
    return *reinterpret_cast<u16*>(&h);
}
__device__ __forceinline__ float b2f(u16 u) {
    union { unsigned u; float f; } v; v.u = ((unsigned)u) << 16;
    return v.f;
}
#define MFMA16(a, b, c) __builtin_amdgcn_mfma_f32_16x16x32_bf16((a), (b), (c), 0, 0, 0)

// async global->LDS, 16B per lane; lds dest wave-uniform base + lane*16
__device__ __forceinline__ void glds16(const u16* g, u16* l) {
    __builtin_amdgcn_global_load_lds(
        (const __attribute__((address_space(1))) unsigned int*)g,
        (__attribute__((address_space(3))) unsigned int*)l,
        16, 0, 0);
}

// ---------------------------------------------------------------------------
// FRAGMENT-PACKED LAYOUT: element (row, k) of [rows][K] lives at
//   (row>>4)*(K*16) + (k>>5)*512 + ((k>>3)&3)*128 + (row&15)*8 + (k&7)
// ---------------------------------------------------------------------------
__device__ __forceinline__ size_t fpk(int row, int k, int K) {
    return (size_t)(row >> 4) * (K * 16) + (k >> 5) * 512 + ((k >> 3) & 3) * 128 +
           (row & 15) * 8 + (k & 7);
}

// ---------------------------------------------------------------------------
// cast x (fp32) -> bf16 fragment-packed (rows = B*T, K = 512)
// ---------------------------------------------------------------------------
__global__ __launch_bounds__(256) void cast_x_k(const float* __restrict__ x,
                                                u16* __restrict__ xb) {
    size_t i = ((size_t)blockIdx.x * 256 + threadIdx.x) * 4;
    float4 v = *(const float4*)(x + i);
    int m = (int)(i >> 9), e = (int)(i & 511);
    ushort4 o;
    o.x = f2b(v.x); o.y = f2b(v.y); o.z = f2b(v.z); o.w = f2b(v.w);
    *(ushort4*)(xb + fpk(m, e, 512)) = o;
}

// ---------------------------------------------------------------------------
// cast mask fp32 -> bf16 (linear)
// ---------------------------------------------------------------------------
__global__ __launch_bounds__(256) void cast_mask_k(const float* __restrict__ m,
                                                   u16* __restrict__ mb) {
    size_t i = ((size_t)blockIdx.x * 256 + threadIdx.x) * 4;
    float4 v = *(const float4*)(m + i);
    ushort4 o;
    o.x = f2b(v.x); o.y = f2b(v.y); o.z = f2b(v.z); o.w = f2b(v.w);
    *(ushort4*)(mb + i) = o;
}

// ---------------------------------------------------------------------------
// cast + transpose weights: W[K][N] fp32 -> fragment-packed Wt (rows=N, K)
// ---------------------------------------------------------------------------
__global__ __launch_bounds__(256) void castT_k(const float* __restrict__ W,
                                               u16* __restrict__ Wt,
                                               int K, int N, float scale) {
    __shared__ float tile[32][33];
    int k0 = blockIdx.y * 32, n0 = blockIdx.x * 32;
    int r = threadIdx.x >> 3, c4 = (threadIdx.x & 7) * 4;
    float4 v = *(const float4*)(W + (size_t)(k0 + r) * N + n0 + c4);
    tile[r][c4] = v.x; tile[r][c4 + 1] = v.y; tile[r][c4 + 2] = v.z; tile[r][c4 + 3] = v.w;
    __syncthreads();
    ushort4 o;
    o.x = f2b(tile[c4 + 0][r] * scale);
    o.y = f2b(tile[c4 + 1][r] * scale);
    o.z = f2b(tile[c4 + 2][r] * scale);
    o.w = f2b(tile[c4 + 3][r] * scale);
    *(ushort4*)(Wt + fpk(n0 + r, k0 + c4, K)) = o;
}

// ---------------------------------------------------------------------------
// MFMA GEMM (m97 structure): 128x128 tile, 4 waves, double-buffered LDS,
// global_load_lds staging.  Vectorized epilogues (wave-private LDS
// transpose -> 16B stores).  EPI: 0=q/k rotary, 1=Vt, 2=gbuf packed, 3=fp32.
// ---------------------------------------------------------------------------
template <int EPI>
__global__ __launch_bounds__(256) void gemm_mfma(const u16* __restrict__ A,
                                                 const u16* __restrict__ Bt,
                                                 void* __restrict__ Cout,
                                                 int K, int N,
                                                 const float* __restrict__ sn,
                                                 const float* __restrict__ cs) {
    __shared__ __align__(16) u16 pool[20480];   // mainloop 2x8192 dbuf; epi reuse
    u16 (*lds)[8192] = (u16(*)[8192])pool;
    int tid = threadIdx.x;
    int lane = tid & 63, wid = tid >> 6;
    int cL = lane & 15, quad = lane >> 4;
    int M0 = blockIdx.y * 8, N0 = blockIdx.x * 8;   // 16-row tile indices
    int m0 = blockIdx.y * 128 + (wid & 1) * 64;
    int n0 = blockIdx.x * 128 + (wid >> 1) * 64;
    const int KT = K * 16;
    const int NK = K >> 5;

#define STAGE(buf, kc) do {                                                        \
        size_t kofs = (size_t)(kc) * 512 + lane * 8;                               \
        glds16(A  + (size_t)(M0 + wid * 2    ) * KT + kofs,                        \
               &lds[buf][(wid * 2    ) * 512]);                                    \
        glds16(A  + (size_t)(M0 + wid * 2 + 1) * KT + kofs,                        \
               &lds[buf][(wid * 2 + 1) * 512]);                                    \
        glds16(Bt + (size_t)(N0 + wid * 2    ) * KT + kofs,                        \
               &lds[buf][4096 + (wid * 2    ) * 512]);                             \
        glds16(Bt + (size_t)(N0 + wid * 2 + 1) * KT + kofs,                        \
               &lds[buf][4096 + (wid * 2 + 1) * 512]);                             \
    } while (0)

    STAGE(0, 0);
    __syncthreads();

    f32x4 acc[4][4] = {};
    int mh = (wid & 1) * 4, nh = (wid >> 1) * 4;
    for (int kc = 0; kc < NK; ++kc) {
        int cur = kc & 1;
        if (kc + 1 < NK) STAGE(cur ^ 1, kc + 1);
        s16x8 af[4], bfr[4];
        int fo = quad * 128 + cL * 8;
        #pragma unroll
        for (int mt = 0; mt < 4; ++mt)
            af[mt] = *(const s16x8*)(&lds[cur][(mh + mt) * 512 + fo]);
        #pragma unroll
        for (int nt = 0; nt < 4; ++nt)
            bfr[nt] = *(const s16x8*)(&lds[cur][4096 + (nh + nt) * 512 + fo]);
        #pragma unroll
        for (int mt = 0; mt < 4; ++mt)
            #pragma unroll
            for (int nt = 0; nt < 4; ++nt)
                acc[mt][nt] = MFMA16(af[mt], bfr[nt], acc[mt][nt]);
        __syncthreads();
    }
#undef STAGE
    u16* ep = pool + wid * 5120;    // wave-private [64 rows][80]

    if (EPI == 0) {
        u16* dst = (u16*)Cout;
        int b = m0 >> 13, h = n0 >> 6, tb = m0 & 8191;
        #pragma unroll
        for (int mt = 0; mt < 4; ++mt)
            #pragma unroll
            for (int nt = 0; nt < 4; ++nt)
                #pragma unroll
                for (int i = 0; i < 4; ++i) {
                    int mrow = mt * 16 + quad * 4 + i;
                    int n = n0 + nt * 16 + cL;
                    float v = acc[mt][nt][i];
                    float p = __shfl_xor(v, 1, 64);
                    int t = tb + mrow, kd = n & 63;
                    float c1 = cs[t * 64 + kd], s1 = sn[t * 64 + kd];
                    float o = (n & 1) ? (v * c1 + p * s1) : (v * c1 - p * s1);
                    ep[mrow * 80 + nt * 16 + cL] = f2b(o);
                }
        u16* dstbh = dst + (size_t)(b * 8 + h) * 524288;
        #pragma unroll
        for (int g2 = 0; g2 < 4; ++g2)
            #pragma unroll
            for (int pass = 0; pass < 2; ++pass) {
                int kcol = pass * 32 + quad * 8;
                s16x8 vv = *(const s16x8*)(ep + (g2 * 16 + cL) * 80 + kcol);
                *(s16x8*)(dstbh + fpk(tb + g2 * 16 + cL, kcol, 64)) = vv;
            }
    } else if (EPI == 1) {
        u16* vt = (u16*)Cout;
        #pragma unroll
        for (int mt = 0; mt < 4; ++mt)
            #pragma unroll
            for (int nt = 0; nt < 4; ++nt) {
                int m = m0 + mt * 16 + quad * 4;
                int n = n0 + nt * 16 + cL;
                int b = m >> 13, t = m & 8191;
                int nn = t >> 8, ccc = t & 255;
                int h = n >> 7, e = n & 127;
                ushort4 pk;
                pk.x = f2b(acc[mt][nt][0]);
                pk.y = f2b(acc[mt][nt][1]);
                pk.z = f2b(acc[mt][nt][2]);
                pk.w = f2b(acc[mt][nt][3]);
                *(ushort4*)(vt + (((size_t)((b * 8 + h) * 32 + nn)) << 15) +
                            fpk(e, ccc, 256)) = pk;
            }
    } else if (EPI == 2) {
        u16* dst = (u16*)Cout;
        #pragma unroll
        for (int mt = 0; mt < 4; ++mt)
            #pragma unroll
            for (int nt = 0; nt < 4; ++nt)
                #pragma unroll
                for (int i = 0; i < 4; ++i)
                    ep[(mt * 16 + quad * 4 + i) * 80 + nt * 16 + cL] =
                        f2b(acc[mt][nt][i]);
        #pragma unroll
        for (int g2 = 0; g2 < 4; ++g2)
            #pragma unroll
            for (int pass = 0; pass < 2; ++pass) {
                int ncol = pass * 32 + quad * 8;
                s16x8 vv = *(const s16x8*)(ep + (g2 * 16 + cL) * 80 + ncol);
                *(s16x8*)(dst + fpk(m0 + g2 * 16 + cL, n0 + ncol, N)) = vv;
            }
    } else {
        float* dst = (float*)Cout;
        #pragma unroll
        for (int mt = 0; mt < 4; ++mt)
            #pragma unroll
            for (int nt = 0; nt < 4; ++nt)
                #pragma unroll
                for (int i = 0; i < 4; ++i)
                    dst[(size_t)(m0 + mt * 16 + quad * 4 + i) * N + n0 + nt * 16 + cL] =
                        acc[mt][nt][i];
    }
}

// ---------------------------------------------------------------------------
// Inner retention, MFMA.  Block = (b, n, h, rtile of 64 rows), 4 waves.
// bf16 mask; vectorized PV epilogue via Ss re-staging.
// ---------------------------------------------------------------------------
__global__ __launch_bounds__(256) void attn_mfma(const u16* __restrict__ qr,
                                                 const u16* __restrict__ kr,
                                                 const u16* __restrict__ vt,
                                                 const u16* __restrict__ maskb,
                                                 u16* __restrict__ ATT,
                                                 float* __restrict__ iscale_g) {
    __shared__ __align__(16) u16 Ss[64][264];
    __shared__ float partial[4][64];
    __shared__ float sInvL[64];
    int p = blockIdx.x;
    int g = (p & 7) | ((p >> 5) << 3);
    int rtile = (p >> 3) & 3;
    int h = g & 7; int n = (g >> 3) & 31; int b = g >> 8;
    int tid = threadIdx.x, lane = tid & 63, w = tid >> 6;
    int cL = lane & 15, quad = lane >> 4;

    size_t qf_bh = (size_t)(b * 8 + h) * 524288;
    f32x4 acc[4][4] = {};
    if (w <= rtile) {
        const u16* Qb = qr + qf_bh + (size_t)(n * 16 + rtile * 4) * 1024;
        const u16* Kb = kr + qf_bh + (size_t)(n * 16 + w * 4) * 1024;
        #pragma unroll
        for (int kt = 0; kt < 2; ++kt) {
            s16x8 af[4], bfr[4];
            size_t ko = (size_t)kt * 512 + quad * 128 + cL * 8;
            #pragma unroll
            for (int mt = 0; mt < 4; ++mt)
                af[mt] = *(const s16x8*)(Qb + (size_t)mt * 1024 + ko);
            #pragma unroll
            for (int nt = 0; nt < 4; ++nt)
                bfr[nt] = *(const s16x8*)(Kb + (size_t)nt * 1024 + ko);
            #pragma unroll
            for (int mt = 0; mt < 4; ++mt)
                #pragma unroll
                for (int nt = 0; nt < 4; ++nt)
                    acc[mt][nt] = MFMA16(af[mt], bfr[nt], acc[mt][nt]);
        }
    }
    float rs[4][4] = {};
    if (w <= rtile) {
        const u16* mb = maskb + ((size_t)h << 16);
        #pragma unroll
        for (int mt = 0; mt < 4; ++mt)
            #pragma unroll
            for (int nt = 0; nt < 4; ++nt)
                #pragma unroll
                for (int i = 0; i < 4; ++i) {
                    int r = rtile * 64 + mt * 16 + quad * 4 + i;
                    int d = w * 64 + nt * 16 + cL;
                    float s = acc[mt][nt][i] * b2f(mb[r * 256 + d]);
                    Ss[mt * 16 + quad * 4 + i][w * 64 + nt * 16 + cL] = f2b(s);
                    rs[mt][i] += fabsf(s);
                }
    }
    #pragma unroll
    for (int mt = 0; mt < 4; ++mt)
        #pragma unroll
        for (int i = 0; i < 4; ++i) {
            float v = rs[mt][i];
            v += __shfl_xor(v, 1, 16);
            v += __shfl_xor(v, 2, 16);
            v += __shfl_xor(v, 4, 16);
            v += __shfl_xor(v, 8, 16);
            if (cL == 0) partial[w][mt * 16 + quad * 4 + i] = v;
        }
    __syncthreads();
    if (tid < 64) {
        float tot = partial[0][tid] + partial[1][tid] + partial[2][tid] + partial[3][tid];
        tot = fmaxf(tot, 1.f);
        iscale_g[((size_t)((b * 32 + n) * 8 + h)) * 256 + rtile * 64 + tid] = tot;
        sInvL[tid] = 1.f / tot;
    }
    __syncthreads();

    f32x4 o[8] = {};
    const u16* Vb = vt + (((size_t)((b * 8 + h) * 32 + n)) << 15);
    int kmax = 2 * (rtile + 1);
    for (int kt = 0; kt < kmax; ++kt) {
        s16x8 a = *(const s16x8*)(&Ss[w * 16 + cL][kt * 32 + quad * 8]);
        #pragma unroll
        for (int nt = 0; nt < 8; ++nt) {
            s16x8 bv = *(const s16x8*)(Vb + (size_t)nt * 4096 + kt * 512 +
                                       quad * 128 + cL * 8);
            o[nt] = MFMA16(a, bv, o[nt]);
        }
    }
    #pragma unroll
    for (int nt = 0; nt < 8; ++nt)
        #pragma unroll
        for (int i = 0; i < 4; ++i) {
            int r = quad * 4 + i;
            Ss[w * 16 + r][nt * 16 + cL] = f2b(o[nt][i] * sInvL[w * 16 + r]);
        }
    size_t obase = ((size_t)b * 8192 + n * 256 + rtile * 64) * 1024 + h * 128;
    #pragma unroll
    for (int pass = 0; pass < 4; ++pass) {
        int e = pass * 32 + quad * 8;
        s16x8 vv = *(const s16x8*)(&Ss[w * 16 + cL][e]);
        *(s16x8*)(ATT + obase + (size_t)(w * 16 + cL) * 1024 + e) = vv;
    }
}

// ---------------------------------------------------------------------------
// Chunk kv summary, MFMA: kvT[e][kd] = sum_c (vid[c]*V[c][e]) * K[c][kd].
// ---------------------------------------------------------------------------
__global__ __launch_bounds__(256) void chunkkv_mfma(const u16* __restrict__ kr,
                                                    const u16* __restrict__ vt,
                                                    const float* __restrict__ vid,
                                                    float* __restrict__ kvT) {
    __shared__ u16 KtL[64][264];
    int bid = blockIdx.x;
    int h = bid & 7; bid >>= 3;
    int n = bid & 31; int b = bid >> 5;
    int tid = threadIdx.x, lane = tid & 63, w = tid >> 6;
    int cL = lane & 15, quad = lane >> 4;
    size_t qf_bh = (size_t)(b * 8 + h) * 524288;
    {
        int c = tid;
        const u16* rp = kr + qf_bh + (size_t)(n * 16 + (c >> 4)) * 1024 + (c & 15) * 8;
        #pragma unroll
        for (int u = 0; u < 8; ++u) {
            s16x8 vv = *(const s16x8*)(rp + (u >> 2) * 512 + (u & 3) * 128);
            #pragma unroll
            for (int j = 0; j < 8; ++j) KtL[u * 8 + j][c] = (u16)vv[j];
        }
    }
    __syncthreads();
    const u16* Vb = vt + (((size_t)((b * 8 + h) * 32 + n)) << 15);
    f32x4 acc[2][4] = {};
    for (int kt = 0; kt < 8; ++kt) {
        float vidv[8];
        #pragma unroll
        for (int j = 0; j < 8; ++j) vidv[j] = vid[h * 256 + kt * 32 + quad * 8 + j];
        s16x8 af[2];
        #pragma unroll
        for (int mt = 0; mt < 2; ++mt) {
            s16x8 raw = *(const s16x8*)(Vb + (size_t)(w * 2 + mt) * 4096 +
                                        kt * 512 + quad * 128 + cL * 8);
            #pragma unroll
            for (int j = 0; j < 8; ++j)
                af[mt][j] = (short)f2b(b2f((u16)raw[j]) * vidv[j]);
        }
        #pragma unroll
        for (int nt = 0; nt < 4; ++nt) {
            s16x8 bv = *(const s16x8*)(&KtL[nt * 16 + cL][kt * 32 + quad * 8]);
            #pragma unroll
            for (int mt = 0; mt < 2; ++mt) acc[mt][nt] = MFMA16(af[mt], bv, acc[mt][nt]);
        }
    }
    float* out = kvT + ((size_t)((b * 32 + n) * 8 + h)) * 8192;
    #pragma unroll
    for (int mt = 0; mt < 2; ++mt)
        #pragma unroll
        for (int nt = 0; nt < 4; ++nt)
            #pragma unroll
            for (int i = 0; i < 4; ++i)
                out[(w * 32 + mt * 16 + quad * 4 + i) * 64 + nt * 16 + cL] = acc[mt][nt][i];
}

// ---------------------------------------------------------------------------
// PARALLEL scan with register double-buffer prefetch.
// ---------------------------------------------------------------------------
__global__ __launch_bounds__(256) void scan_par(const float* __restrict__ kvT,
                                                u16* __restrict__ kvrecb,
                                                const float* __restrict__ cdv,
                                                float* __restrict__ cscale) {
    int bid = blockIdx.x;
    int n = bid & 31; bid >>= 5;
    int h = bid & 7; int b = bid >> 3;
    int tid = threadIdx.x, lane = tid & 63, g = tid >> 6;
    float cd = cdv[h];
    float st[32], cur[32], nxt[32];
    #pragma unroll
    for (int i = 0; i < 32; ++i) { st[i] = 0.f; nxt[i] = 0.f; }
    if (n > 0) {
        size_t base0 = ((size_t)((b * 32) * 8 + h)) * 8192;
        #pragma unroll
        for (int i = 0; i < 32; ++i) cur[i] = kvT[base0 + (g + 4 * i) * 64 + lane];
    }
    for (int j = 0; j < n; ++j) {
        if (j + 1 < n) {
            size_t basen = ((size_t)((b * 32 + j + 1) * 8 + h)) * 8192;
            #pragma unroll
            for (int i = 0; i < 32; ++i) nxt[i] = kvT[basen + (g + 4 * i) * 64 + lane];
        }
        #pragma unroll
        for (int i = 0; i < 32; ++i) st[i] = st[i] * cd + cur[i];
        #pragma unroll
        for (int i = 0; i < 32; ++i) cur[i] = nxt[i];
    }
    __shared__ float esum[128];
    __shared__ float sSc;
    #pragma unroll
    for (int i = 0; i < 32; ++i) {
        float s = fabsf(st[i]);
        s += __shfl_xor(s, 1, 64);
        s += __shfl_xor(s, 2, 64);
        s += __shfl_xor(s, 4, 64);
        s += __shfl_xor(s, 8, 64);
        s += __shfl_xor(s, 16, 64);
        s += __shfl_xor(s, 32, 64);
        if (lane == 0) esum[g + 4 * i] = s;
    }
    __syncthreads();
    if (tid < 64) {
        float m1 = fmaxf(esum[tid], esum[tid + 64]);
        m1 = fmaxf(m1, __shfl_xor(m1, 1, 64));
        m1 = fmaxf(m1, __shfl_xor(m1, 2, 64));
        m1 = fmaxf(m1, __shfl_xor(m1, 4, 64));
        m1 = fmaxf(m1, __shfl_xor(m1, 8, 64));
        m1 = fmaxf(m1, __shfl_xor(m1, 16, 64));
        m1 = fmaxf(m1, __shfl_xor(m1, 32, 64));
        if (tid == 0) sSc = fmaxf(m1, 1.f);
    }
    __syncthreads();
    float scale = sSc;
    float inv = 1.f / scale;
    size_t baseN = ((size_t)((b * 32 + n) * 8 + h)) * 8192;
    #pragma unroll
    for (int i = 0; i < 32; ++i) {
        int e = g + 4 * i;
        kvrecb[baseN + ((size_t)(lane >> 3) * 128 + e) * 8 + (lane & 7)] = f2b(st[i] * inv);
    }
    if (tid == 0) cscale[(b * 32 + n) * 8 + h] = scale;
}

// ---------------------------------------------------------------------------
// Cross output + combine, MFMA.  Block = (b,n,h), wave owns 64 chunk rows.
// Vectorized RMW via wave-private LDS transpose.
// ---------------------------------------------------------------------------
__global__ __launch_bounds__(256) void cross_mfma(const u16* __restrict__ qr,
                                                  const u16* __restrict__ kvrecb,
                                                  const float* __restrict__ iscale_g,
                                                  const float* __restrict__ cscale_g,
                                                  const float* __restrict__ qid,
                                                  u16* __restrict__ ATT) {
    __shared__ __align__(16) u16 X[4][4608];   // per wave [64 rows][72]
    int bid = blockIdx.x;
    int h = bid & 7; bid >>= 3;
    int n = bid & 31; int b = bid >> 5;
    int tid = threadIdx.x, lane = tid & 63, w = tid >> 6;
    int cL = lane & 15, quad = lane >> 4;
    size_t qf_bh = (size_t)(b * 8 + h) * 524288;
    const u16* Qb = qr + qf_bh + (size_t)(n * 16 + w * 4) * 1024;
    const u16* KVb = kvrecb + ((size_t)((b * 32 + n) * 8 + h)) * 8192;
    s16x8 af[4][2];
    #pragma unroll
    for (int mt = 0; mt < 4; ++mt)
        #pragma unroll
        for (int kt = 0; kt < 2; ++kt)
            af[mt][kt] = *(const s16x8*)(Qb + (size_t)mt * 1024 + kt * 512 +
                                         quad * 128 + cL * 8);
    float csc = cscale_g[(b * 32 + n) * 8 + h];
    size_t ibase = ((size_t)((b * 32 + n) * 8 + h)) * 256 + w * 64;
    size_t obase = ((size_t)(b * 8192 + n * 256 + w * 64)) * 1024 + h * 128;
    #pragma unroll
    for (int hn = 0; hn < 2; ++hn) {
        f32x4 acc[4][4] = {};
        #pragma unroll
        for (int kt = 0; kt < 2; ++kt)
            #pragma unroll
            for (int nt = 0; nt < 4; ++nt) {
                int e = (hn * 4 + nt) * 16 + cL;
                s16x8 bv = *(const s16x8*)(KVb + ((size_t)(kt * 4 + quad) * 128 + e) * 8);
                #pragma unroll
                for (int mt = 0; mt < 4; ++mt)
                    acc[mt][nt] = MFMA16(af[mt][kt], bv, acc[mt][nt]);
            }
        #pragma unroll
        for (int mt = 0; mt < 4; ++mt)
            #pragma unroll
            for (int i = 0; i < 4; ++i) {
                int r = mt * 16 + quad * 4 + i;
                float isc = iscale_g[ibase + r];
                float alls = fmaxf(isc, csc);
                float fC = (csc / alls) * qid[h * 256 + w * 64 + r];
                #pragma unroll
                for (int nt = 0; nt < 4; ++nt)
                    X[w][r * 72 + nt * 16 + cL] = f2b(acc[mt][nt][i] * fC);
            }
        #pragma unroll
        for (int g2 = 0; g2 < 4; ++g2)
            #pragma unroll
            for (int pass = 0; pass < 2; ++pass) {
                int r2 = g2 * 16 + cL;
                float isc2 = iscale_g[ibase + r2];
                float fI2 = isc2 / fmaxf(isc2, csc);
                int e = pass * 32 + quad * 8;
                s16x8 sv = *(const s16x8*)(&X[w][r2 * 72 + e]);
                size_t oi = obase + (size_t)r2 * 1024 + hn * 64 + e;
                s16x8 pv = *(const s16x8*)(ATT + oi);
                s16x8 ov;
                #pragma unroll
                for (int j = 0; j < 8; ++j)
                    ov[j] = (short)f2b(b2f((u16)pv[j]) * fI2 + b2f((u16)sv[j]));
                *(s16x8*)(ATT + oi) = ov;
            }
    }
}

// ---------------------------------------------------------------------------
// PER-HEAD RMS norm (HD=128) + SiLU gate, in place over g (round-4 version).
// One block per 16-row fpk TILE of g (16 x 1024 = 32KB), grid 2048.
// ---------------------------------------------------------------------------
__global__ __launch_bounds__(256) void rms_silu(const u16* __restrict__ ATT,
                                                u16* __restrict__ g) {
    __shared__ u16 att_s[16 * 1036];       // stride 1036 shorts (518 words, %32=6)
    __shared__ float rmsv[16][8];
    int tile = blockIdx.x;
    int tid = threadIdx.x;
    size_t abase = (size_t)tile * 16 * 1024;
    int head = tid >> 5;                   // 8 groups of 32 threads = 8 heads
    #pragma unroll
    for (int jj = 0; jj < 16; ++jj) {
        ushort4 v = *(const ushort4*)(ATT + abase + (size_t)jj * 1024 + tid * 4);
        *(ushort4*)(att_s + jj * 1036 + tid * 4) = v;
        float x0 = b2f(v.x), x1 = b2f(v.y), x2 = b2f(v.z), x3 = b2f(v.w);
        float ss = x0 * x0 + x1 * x1 + x2 * x2 + x3 * x3;
        ss += __shfl_xor(ss, 1, 32);
        ss += __shfl_xor(ss, 2, 32);
        ss += __shfl_xor(ss, 4, 32);
        ss += __shfl_xor(ss, 8, 32);
        ss += __shfl_xor(ss, 16, 32);
        if ((tid & 31) == 0)
            rmsv[jj][head] = rsqrtf(ss * (1.f / 128.f) + 1e-6f);
    }
    __syncthreads();
    size_t gbase = (size_t)tile * 16384;
    #pragma unroll
    for (int it = 0; it < 16; ++it) {
        int p = it * 1024 + tid * 4;
        int e = ((p >> 9) << 5) | (((p >> 7) & 3) << 3) | (p & 7);
        int r = (p >> 3) & 15;
        ushort4 gv = *(const ushort4*)(g + gbase + p);
        ushort4 av = *(const ushort4*)(att_s + r * 1036 + e);
        float rms = rmsv[r][e >> 7];
        float x0 = b2f(av.x), x1 = b2f(av.y), x2 = b2f(av.z), x3 = b2f(av.w);
        float g0 = b2f(gv.x), g1 = b2f(gv.y), g2 = b2f(gv.z), g3 = b2f(gv.w);
        ushort4 ov;
        ov.x = f2b((g0 / (1.f + __expf(-g0))) * x0 * rms);
        ov.y = f2b((g1 / (1.f + __expf(-g1))) * x1 * rms);
        ov.z = f2b((g2 / (1.f + __expf(-g2))) * x2 * rms);
        ov.w = f2b((g3 / (1.f + __expf(-g3))) * x3 * rms);
        *(ushort4*)(g + gbase + p) = ov;
    }
}

// ---------------------------------------------------------------------------
extern "C" void kernel_launch(void* const* d_in, const int* in_sizes, int n_in,
                              void* d_out, int out_size, void* d_ws, size_t ws_size,
                              hipStream_t stream) {
    const float* x    = (const float*)d_in[0];
    const float* sn   = (const float*)d_in[1];
    const float* cs   = (const float*)d_in[2];
    const float* mask = (const float*)d_in[3];
    const float* cdv  = (const float*)d_in[4];
    const float* qid  = (const float*)d_in[5];
    const float* vid  = (const float*)d_in[6];
    const float* Wq   = (const float*)d_in[7];
    const float* Wk   = (const float*)d_in[8];
    const float* Wv   = (const float*)d_in[9];
    const float* Wg   = (const float*)d_in[10];
    const float* Wo   = (const float*)d_in[11];
    float* out = (float*)d_out;

    char* w = (char*)d_ws;
    u16* qr     = (u16*)w;   w += (size_t)16777216 * 2;
    u16* kr     = (u16*)w;   w += (size_t)16777216 * 2;
    u16* vt     = (u16*)w;   w += (size_t)33554432 * 2;
    u16* xbf    = (u16*)w;   w += (size_t)16777216 * 2;
    u16* wqT    = (u16*)w;   w += (size_t)262144 * 2;
    u16* wkT    = (u16*)w;   w += (size_t)262144 * 2;
    u16* wvT    = (u16*)w;   w += (size_t)524288 * 2;
    u16* wgT    = (u16*)w;   w += (size_t)524288 * 2;
    u16* woT    = (u16*)w;   w += (size_t)524288 * 2;
    float* kvT  = (float*)w; w += (size_t)8388608 * 4;
    u16* kvrecb = (u16*)w;   w += (size_t)8388608 * 2;
    float* iscale = (float*)w; w += (size_t)262144 * 4;
    float* cscale = (float*)w; w += (size_t)1024 * 4;
    u16* maskb  = (u16*)w;   w += (size_t)524288 * 2;   // bf16 mask (H,C,C)

    u16* gbuf = qr;            // 67 MB over dead qr+kr after cross_combine
    u16* ATT  = (u16*)d_out;   // 67 MB bf16 scratch inside the output buffer

    dim3 blk(256);
    cast_x_k<<<dim3(16384), blk, 0, stream>>>(x, xbf);
    cast_mask_k<<<dim3(512), blk, 0, stream>>>(mask, maskb);
    castT_k<<<dim3(16, 16), blk, 0, stream>>>(Wq, wqT, 512, 512, 1.0f);
    castT_k<<<dim3(16, 16), blk, 0, stream>>>(Wk, wkT, 512, 512, 0.125f);
    castT_k<<<dim3(32, 16), blk, 0, stream>>>(Wv, wvT, 512, 1024, 1.0f);
    castT_k<<<dim3(32, 16), blk, 0, stream>>>(Wg, wgT, 512, 1024, 1.0f);
    castT_k<<<dim3(16, 32), blk, 0, stream>>>(Wo, woT, 1024, 512, 1.0f);
    gemm_mfma<0><<<dim3(4, 256), blk, 0, stream>>>(xbf, wqT, qr, 512, 512, sn, cs);
    gemm_mfma<0><<<dim3(4, 256), blk, 0, stream>>>(xbf, wkT, kr, 512, 512, sn, cs);
    gemm_mfma<1><<<dim3(8, 256), blk, 0, stream>>>(xbf, wvT, vt, 512, 1024, nullptr, nullptr);
    attn_mfma<<<dim3(4096), blk, 0, stream>>>(qr, kr, vt, maskb, ATT, iscale);
    chunkkv_mfma<<<dim3(1024), blk, 0, stream>>>(kr, vt, vid, kvT);
    scan_par<<<dim3(1024), blk, 0, stream>>>(kvT, kvrecb, cdv, cscale);
    cross_mfma<<<dim3(1024), blk, 0, stream>>>(qr, kvrecb, iscale, cscale, qid, ATT);
    gemm_mfma<2><<<dim3(8, 256), blk, 0, stream>>>(xbf, wgT, gbuf, 512, 1024, nullptr, nullptr);
    rms_silu<<<dim3(2048), blk, 0, stream>>>(ATT, gbuf);
    gemm_mfma<3><<<dim3(4, 256), blk, 0, stream>>>(gbuf, woT, out, 1024, 512, nullptr, nullptr);
}

// Round 9
// 589.576 us; speedup vs baseline: 1.1634x; 1.0900x over previous
//
#include <hip/hip_runtime.h>
#include <hip/hip_bf16.h>
#include <cmath>

// Problem constants
#define Bz 4
#define Tt 8192
#define Ee 512
#define Hh 8
#define Cc 256
#define KD 64          // E/H
#define HD 128         // E*VF/H
#define NC 32          // T/C
#define EV 1024        // E*VF
#define Mrows (Bz*Tt)  // 32768

typedef unsigned short u16;
typedef __attribute__((ext_vector_type(4))) float f32x4;
typedef __attribute__((ext_vector_type(8))) short s16x8;

__device__ __forceinline__ u16 f2b(float f) {
    __hip_bfloat16 h = __float2bfloat16(f);   // RNE
    return *reinterpret_cast<u16*>(&h);
}
__device__ __forceinline__ float b2f(u16 u) {
    union { unsigned u; float f; } v; v.u = ((unsigned)u) << 16;
    return v.f;
}
#define MFMA16(a, b, c) __builtin_amdgcn_mfma_f32_16x16x32_bf16((a), (b), (c), 0, 0, 0)

// async global->LDS, 16B per lane; lds dest wave-uniform base + lane*16
__device__ __forceinline__ void glds16(const u16* g, u16* l) {
    __builtin_amdgcn_global_load_lds(
        (const __attribute__((address_space(1))) unsigned int*)g,
        (__attribute__((address_space(3))) unsigned int*)l,
        16, 0, 0);
}

// ---------------------------------------------------------------------------
// FRAGMENT-PACKED LAYOUT: element (row, k) of [rows][K] lives at
//   (row>>4)*(K*16) + (k>>5)*512 + ((k>>3)&3)*128 + (row&15)*8 + (k&7)
// ---------------------------------------------------------------------------
__device__ __forceinline__ size_t fpk(int row, int k, int K) {
    return (size_t)(row >> 4) * (K * 16) + (k >> 5) * 512 + ((k >> 3) & 3) * 128 +
           (row & 15) * 8 + (k & 7);
}

// ---------------------------------------------------------------------------
// cast x (fp32) -> bf16 fragment-packed (rows = B*T, K = 512)
// ---------------------------------------------------------------------------
__global__ __launch_bounds__(256) void cast_x_k(const float* __restrict__ x,
                                                u16* __restrict__ xb) {
    size_t i = ((size_t)blockIdx.x * 256 + threadIdx.x) * 4;
    float4 v = *(const float4*)(x + i);
    int m = (int)(i >> 9), e = (int)(i & 511);
    ushort4 o;
    o.x = f2b(v.x); o.y = f2b(v.y); o.z = f2b(v.z); o.w = f2b(v.w);
    *(ushort4*)(xb + fpk(m, e, 512)) = o;
}

// ---------------------------------------------------------------------------
// cast mask fp32 -> bf16 (linear)
// ---------------------------------------------------------------------------
__global__ __launch_bounds__(256) void cast_mask_k(const float* __restrict__ m,
                                                   u16* __restrict__ mb) {
    size_t i = ((size_t)blockIdx.x * 256 + threadIdx.x) * 4;
    float4 v = *(const float4*)(m + i);
    ushort4 o;
    o.x = f2b(v.x); o.y = f2b(v.y); o.z = f2b(v.z); o.w = f2b(v.w);
    *(ushort4*)(mb + i) = o;
}

// ---------------------------------------------------------------------------
// cast + transpose weights: W[K][N] fp32 -> fragment-packed Wt (rows=N, K)
// ---------------------------------------------------------------------------
__global__ __launch_bounds__(256) void castT_k(const float* __restrict__ W,
                                               u16* __restrict__ Wt,
                                               int K, int N, float scale) {
    __shared__ float tile[32][33];
    int k0 = blockIdx.y * 32, n0 = blockIdx.x * 32;
    int r = threadIdx.x >> 3, c4 = (threadIdx.x & 7) * 4;
    float4 v = *(const float4*)(W + (size_t)(k0 + r) * N + n0 + c4);
    tile[r][c4] = v.x; tile[r][c4 + 1] = v.y; tile[r][c4 + 2] = v.z; tile[r][c4 + 3] = v.w;
    __syncthreads();
    ushort4 o;
    o.x = f2b(tile[c4 + 0][r] * scale);
    o.y = f2b(tile[c4 + 1][r] * scale);
    o.z = f2b(tile[c4 + 2][r] * scale);
    o.w = f2b(tile[c4 + 3][r] * scale);
    *(ushort4*)(Wt + fpk(n0 + r, k0 + c4, K)) = o;
}

// ---------------------------------------------------------------------------
// MERGED projection GEMM: A=xbf, Bt = [wqT|wkT|wvT] (N=2048, contiguous,
// fragment-packed).  m97 mainloop.  Epilogue per 128-col block:
//   n0<512: rotary->qr ; 512<=n0<1024: rotary->kr ; else EPI1->vt.
// ---------------------------------------------------------------------------
__global__ __launch_bounds__(256) void gemm_proj(const u16* __restrict__ A,
                                                 const u16* __restrict__ Bt,
                                                 u16* __restrict__ qr,
                                                 u16* __restrict__ kr,
                                                 u16* __restrict__ vt,
                                                 const float* __restrict__ sn,
                                                 const float* __restrict__ cs) {
    __shared__ __align__(16) u16 pool[20480];
    u16 (*lds)[8192] = (u16(*)[8192])pool;
    const int K = 512;
    int tid = threadIdx.x;
    int lane = tid & 63, wid = tid >> 6;
    int cL = lane & 15, quad = lane >> 4;
    int M0 = blockIdx.y * 8, N0 = blockIdx.x * 8;
    int m0 = blockIdx.y * 128 + (wid & 1) * 64;
    int n0 = blockIdx.x * 128 + (wid >> 1) * 64;
    const int KT = K * 16;
    const int NK = K >> 5;

#define STAGE(buf, kc) do {                                                        \
        size_t kofs = (size_t)(kc) * 512 + lane * 8;                               \
        glds16(A  + (size_t)(M0 + wid * 2    ) * KT + kofs,                        \
               &lds[buf][(wid * 2    ) * 512]);                                    \
        glds16(A  + (size_t)(M0 + wid * 2 + 1) * KT + kofs,                        \
               &lds[buf][(wid * 2 + 1) * 512]);                                    \
        glds16(Bt + (size_t)(N0 + wid * 2    ) * KT + kofs,                        \
               &lds[buf][4096 + (wid * 2    ) * 512]);                             \
        glds16(Bt + (size_t)(N0 + wid * 2 + 1) * KT + kofs,                        \
               &lds[buf][4096 + (wid * 2 + 1) * 512]);                             \
    } while (0)

    STAGE(0, 0);
    __syncthreads();
    f32x4 acc[4][4] = {};
    int mh = (wid & 1) * 4, nh = (wid >> 1) * 4;
    for (int kc = 0; kc < NK; ++kc) {
        int cur = kc & 1;
        if (kc + 1 < NK) STAGE(cur ^ 1, kc + 1);
        s16x8 af[4], bfr[4];
        int fo = quad * 128 + cL * 8;
        #pragma unroll
        for (int mt = 0; mt < 4; ++mt)
            af[mt] = *(const s16x8*)(&lds[cur][(mh + mt) * 512 + fo]);
        #pragma unroll
        for (int nt = 0; nt < 4; ++nt)
            bfr[nt] = *(const s16x8*)(&lds[cur][4096 + (nh + nt) * 512 + fo]);
        #pragma unroll
        for (int mt = 0; mt < 4; ++mt)
            #pragma unroll
            for (int nt = 0; nt < 4; ++nt)
                acc[mt][nt] = MFMA16(af[mt], bfr[nt], acc[mt][nt]);
        __syncthreads();
    }
#undef STAGE
    u16* ep = pool + wid * 5120;    // wave-private [64 rows][80]

    if (n0 < 1024) {
        // rotary q/k path (wave's 64 cols = exactly one head)
        int b = m0 >> 13, tb = m0 & 8191;
        int hq = (n0 & 511) >> 6;
        u16* dstbh = (n0 < 512 ? qr : kr) + (size_t)(b * 8 + hq) * 524288;
        #pragma unroll
        for (int mt = 0; mt < 4; ++mt)
            #pragma unroll
            for (int nt = 0; nt < 4; ++nt)
                #pragma unroll
                for (int i = 0; i < 4; ++i) {
                    int mrow = mt * 16 + quad * 4 + i;
                    int n = n0 + nt * 16 + cL;
                    float v = acc[mt][nt][i];
                    float p = __shfl_xor(v, 1, 64);
                    int t = tb + mrow, kd = n & 63;
                    float c1 = cs[t * 64 + kd], s1 = sn[t * 64 + kd];
                    float o = (n & 1) ? (v * c1 + p * s1) : (v * c1 - p * s1);
                    ep[mrow * 80 + nt * 16 + cL] = f2b(o);
                }
        #pragma unroll
        for (int g2 = 0; g2 < 4; ++g2)
            #pragma unroll
            for (int pass = 0; pass < 2; ++pass) {
                int kcol = pass * 32 + quad * 8;
                s16x8 vv = *(const s16x8*)(ep + (g2 * 16 + cL) * 80 + kcol);
                *(s16x8*)(dstbh + fpk(tb + g2 * 16 + cL, kcol, 64)) = vv;
            }
    } else {
        // v path (EPI1), n_v in [0,1024)
        #pragma unroll
        for (int mt = 0; mt < 4; ++mt)
            #pragma unroll
            for (int nt = 0; nt < 4; ++nt) {
                int m = m0 + mt * 16 + quad * 4;
                int nv = (n0 - 1024) + nt * 16 + cL;
                int b = m >> 13, t = m & 8191;
                int nn = t >> 8, ccc = t & 255;
                int h = nv >> 7, e = nv & 127;
                ushort4 pk;
                pk.x = f2b(acc[mt][nt][0]);
                pk.y = f2b(acc[mt][nt][1]);
                pk.z = f2b(acc[mt][nt][2]);
                pk.w = f2b(acc[mt][nt][3]);
                *(ushort4*)(vt + (((size_t)((b * 8 + h) * 32 + nn)) << 15) +
                            fpk(e, ccc, 256)) = pk;
            }
    }
}

// ---------------------------------------------------------------------------
// MFMA GEMM (m97 structure) for g (EPI=2, packed) and out (EPI=3, fp32).
// ---------------------------------------------------------------------------
template <int EPI>
__global__ __launch_bounds__(256) void gemm_mfma(const u16* __restrict__ A,
                                                 const u16* __restrict__ Bt,
                                                 void* __restrict__ Cout,
                                                 int K, int N) {
    __shared__ __align__(16) u16 pool[20480];
    u16 (*lds)[8192] = (u16(*)[8192])pool;
    int tid = threadIdx.x;
    int lane = tid & 63, wid = tid >> 6;
    int cL = lane & 15, quad = lane >> 4;
    int M0 = blockIdx.y * 8, N0 = blockIdx.x * 8;
    int m0 = blockIdx.y * 128 + (wid & 1) * 64;
    int n0 = blockIdx.x * 128 + (wid >> 1) * 64;
    const int KT = K * 16;
    const int NK = K >> 5;

#define STAGE(buf, kc) do {                                                        \
        size_t kofs = (size_t)(kc) * 512 + lane * 8;                               \
        glds16(A  + (size_t)(M0 + wid * 2    ) * KT + kofs,                        \
               &lds[buf][(wid * 2    ) * 512]);                                    \
        glds16(A  + (size_t)(M0 + wid * 2 + 1) * KT + kofs,                        \
               &lds[buf][(wid * 2 + 1) * 512]);                                    \
        glds16(Bt + (size_t)(N0 + wid * 2    ) * KT + kofs,                        \
               &lds[buf][4096 + (wid * 2    ) * 512]);                             \
        glds16(Bt + (size_t)(N0 + wid * 2 + 1) * KT + kofs,                        \
               &lds[buf][4096 + (wid * 2 + 1) * 512]);                             \
    } while (0)

    STAGE(0, 0);
    __syncthreads();
    f32x4 acc[4][4] = {};
    int mh = (wid & 1) * 4, nh = (wid >> 1) * 4;
    for (int kc = 0; kc < NK; ++kc) {
        int cur = kc & 1;
        if (kc + 1 < NK) STAGE(cur ^ 1, kc + 1);
        s16x8 af[4], bfr[4];
        int fo = quad * 128 + cL * 8;
        #pragma unroll
        for (int mt = 0; mt < 4; ++mt)
            af[mt] = *(const s16x8*)(&lds[cur][(mh + mt) * 512 + fo]);
        #pragma unroll
        for (int nt = 0; nt < 4; ++nt)
            bfr[nt] = *(const s16x8*)(&lds[cur][4096 + (nh + nt) * 512 + fo]);
        #pragma unroll
        for (int mt = 0; mt < 4; ++mt)
            #pragma unroll
            for (int nt = 0; nt < 4; ++nt)
                acc[mt][nt] = MFMA16(af[mt], bfr[nt], acc[mt][nt]);
        __syncthreads();
    }
#undef STAGE
    u16* ep = pool + wid * 5120;

    if (EPI == 2) {
        u16* dst = (u16*)Cout;
        #pragma unroll
        for (int mt = 0; mt < 4; ++mt)
            #pragma unroll
            for (int nt = 0; nt < 4; ++nt)
                #pragma unroll
                for (int i = 0; i < 4; ++i)
                    ep[(mt * 16 + quad * 4 + i) * 80 + nt * 16 + cL] =
                        f2b(acc[mt][nt][i]);
        #pragma unroll
        for (int g2 = 0; g2 < 4; ++g2)
            #pragma unroll
            for (int pass = 0; pass < 2; ++pass) {
                int ncol = pass * 32 + quad * 8;
                s16x8 vv = *(const s16x8*)(ep + (g2 * 16 + cL) * 80 + ncol);
                *(s16x8*)(dst + fpk(m0 + g2 * 16 + cL, n0 + ncol, N)) = vv;
            }
    } else {
        float* dst = (float*)Cout;
        #pragma unroll
        for (int mt = 0; mt < 4; ++mt)
            #pragma unroll
            for (int nt = 0; nt < 4; ++nt)
                #pragma unroll
                for (int i = 0; i < 4; ++i)
                    dst[(size_t)(m0 + mt * 16 + quad * 4 + i) * N + n0 + nt * 16 + cL] =
                        acc[mt][nt][i];
    }
}

// ---------------------------------------------------------------------------
// FUSED inner retention + cross output.  Block = (b,n,h,rtile), 4 waves.
// Runs AFTER chunkkv+scan.  final = innerRaw/alls + (Q@kvrecb)*(csc/alls)*qid
// where alls = max(isc, csc); isc stays block-local (never hits global).
// ---------------------------------------------------------------------------
__global__ __launch_bounds__(256) void attn_cross(const u16* __restrict__ qr,
                                                  const u16* __restrict__ kr,
                                                  const u16* __restrict__ vt,
                                                  const u16* __restrict__ maskb,
                                                  const u16* __restrict__ kvrecb,
                                                  const float* __restrict__ cscale_g,
                                                  const float* __restrict__ qid,
                                                  u16* __restrict__ ATT) {
    __shared__ __align__(16) u16 Ss[64][264];
    __shared__ float partial[4][64];
    __shared__ float sIsc[64];
    int p = blockIdx.x;
    int g = (p & 7) | ((p >> 5) << 3);
    int rtile = (p >> 3) & 3;
    int h = g & 7; int n = (g >> 3) & 31; int b = g >> 8;
    int tid = threadIdx.x, lane = tid & 63, w = tid >> 6;
    int cL = lane & 15, quad = lane >> 4;

    size_t qf_bh = (size_t)(b * 8 + h) * 524288;
    f32x4 acc[4][4] = {};
    if (w <= rtile) {
        const u16* Qb = qr + qf_bh + (size_t)(n * 16 + rtile * 4) * 1024;
        const u16* Kb = kr + qf_bh + (size_t)(n * 16 + w * 4) * 1024;
        #pragma unroll
        for (int kt = 0; kt < 2; ++kt) {
            s16x8 af[4], bfr[4];
            size_t ko = (size_t)kt * 512 + quad * 128 + cL * 8;
            #pragma unroll
            for (int mt = 0; mt < 4; ++mt)
                af[mt] = *(const s16x8*)(Qb + (size_t)mt * 1024 + ko);
            #pragma unroll
            for (int nt = 0; nt < 4; ++nt)
                bfr[nt] = *(const s16x8*)(Kb + (size_t)nt * 1024 + ko);
            #pragma unroll
            for (int mt = 0; mt < 4; ++mt)
                #pragma unroll
                for (int nt = 0; nt < 4; ++nt)
                    acc[mt][nt] = MFMA16(af[mt], bfr[nt], acc[mt][nt]);
        }
    }
    float rs[4][4] = {};
    if (w <= rtile) {
        const u16* mb = maskb + ((size_t)h << 16);
        #pragma unroll
        for (int mt = 0; mt < 4; ++mt)
            #pragma unroll
            for (int nt = 0; nt < 4; ++nt)
                #pragma unroll
                for (int i = 0; i < 4; ++i) {
                    int r = rtile * 64 + mt * 16 + quad * 4 + i;
                    int d = w * 64 + nt * 16 + cL;
                    float s = acc[mt][nt][i] * b2f(mb[r * 256 + d]);
                    Ss[mt * 16 + quad * 4 + i][w * 64 + nt * 16 + cL] = f2b(s);
                    rs[mt][i] += fabsf(s);
                }
    }
    #pragma unroll
    for (int mt = 0; mt < 4; ++mt)
        #pragma unroll
        for (int i = 0; i < 4; ++i) {
            float v = rs[mt][i];
            v += __shfl_xor(v, 1, 16);
            v += __shfl_xor(v, 2, 16);
            v += __shfl_xor(v, 4, 16);
            v += __shfl_xor(v, 8, 16);
            if (cL == 0) partial[w][mt * 16 + quad * 4 + i] = v;
        }
    __syncthreads();
    if (tid < 64) {
        float tot = partial[0][tid] + partial[1][tid] + partial[2][tid] + partial[3][tid];
        sIsc[tid] = fmaxf(tot, 1.f);
    }
    __syncthreads();

    // PV: innerRaw
    f32x4 o[8] = {};
    const u16* Vb = vt + (((size_t)((b * 8 + h) * 32 + n)) << 15);
    int kmax = 2 * (rtile + 1);
    for (int kt = 0; kt < kmax; ++kt) {
        s16x8 a = *(const s16x8*)(&Ss[w * 16 + cL][kt * 32 + quad * 8]);
        #pragma unroll
        for (int nt = 0; nt < 8; ++nt) {
            s16x8 bv = *(const s16x8*)(Vb + (size_t)nt * 4096 + kt * 512 +
                                       quad * 128 + cL * 8);
            o[nt] = MFMA16(a, bv, o[nt]);
        }
    }

    // cross: wave's own 16-row Q strip @ kvrecb
    f32x4 acc2[8] = {};
    {
        const u16* Qc = qr + qf_bh + (size_t)(n * 16 + rtile * 4 + w) * 1024;
        const u16* KVb = kvrecb + ((size_t)((b * 32 + n) * 8 + h)) * 8192;
        s16x8 afc[2];
        afc[0] = *(const s16x8*)(Qc + quad * 128 + cL * 8);
        afc[1] = *(const s16x8*)(Qc + 512 + quad * 128 + cL * 8);
        #pragma unroll
        for (int kt = 0; kt < 2; ++kt)
            #pragma unroll
            for (int nt = 0; nt < 8; ++nt) {
                s16x8 bv = *(const s16x8*)(KVb +
                            ((size_t)(kt * 4 + quad) * 128 + nt * 16 + cL) * 8);
                acc2[nt] = MFMA16(afc[kt], bv, acc2[nt]);
            }
    }

    // combine + stage + vector store
    float csc = cscale_g[(b * 32 + n) * 8 + h];
    #pragma unroll
    for (int i = 0; i < 4; ++i) {
        int rloc = w * 16 + quad * 4 + i;
        float isc = sIsc[rloc];
        float alls = fmaxf(isc, csc);
        float invA = 1.f / alls;
        float fC = csc * invA * qid[h * 256 + rtile * 64 + rloc];
        #pragma unroll
        for (int nt = 0; nt < 8; ++nt)
            Ss[w * 16 + quad * 4 + i][nt * 16 + cL] =
                f2b(o[nt][i] * invA + acc2[nt][i] * fC);
    }
    size_t obase = ((size_t)b * 8192 + n * 256 + rtile * 64) * 1024 + h * 128;
    #pragma unroll
    for (int pass = 0; pass < 4; ++pass) {
        int e = pass * 32 + quad * 8;
        s16x8 vv = *(const s16x8*)(&Ss[w * 16 + cL][e]);
        *(s16x8*)(ATT + obase + (size_t)(w * 16 + cL) * 1024 + e) = vv;
    }
}

// ---------------------------------------------------------------------------
// Chunk kv summary, MFMA: kvT[e][kd] = sum_c (vid[c]*V[c][e]) * K[c][kd].
// ---------------------------------------------------------------------------
__global__ __launch_bounds__(256) void chunkkv_mfma(const u16* __restrict__ kr,
                                                    const u16* __restrict__ vt,
                                                    const float* __restrict__ vid,
                                                    float* __restrict__ kvT) {
    __shared__ u16 KtL[64][264];
    int bid = blockIdx.x;
    int h = bid & 7; bid >>= 3;
    int n = bid & 31; int b = bid >> 5;
    int tid = threadIdx.x, lane = tid & 63, w = tid >> 6;
    int cL = lane & 15, quad = lane >> 4;
    size_t qf_bh = (size_t)(b * 8 + h) * 524288;
    {
        int c = tid;
        const u16* rp = kr + qf_bh + (size_t)(n * 16 + (c >> 4)) * 1024 + (c & 15) * 8;
        #pragma unroll
        for (int u = 0; u < 8; ++u) {
            s16x8 vv = *(const s16x8*)(rp + (u >> 2) * 512 + (u & 3) * 128);
            #pragma unroll
            for (int j = 0; j < 8; ++j) KtL[u * 8 + j][c] = (u16)vv[j];
        }
    }
    __syncthreads();
    const u16* Vb = vt + (((size_t)((b * 8 + h) * 32 + n)) << 15);
    f32x4 acc[2][4] = {};
    for (int kt = 0; kt < 8; ++kt) {
        float vidv[8];
        #pragma unroll
        for (int j = 0; j < 8; ++j) vidv[j] = vid[h * 256 + kt * 32 + quad * 8 + j];
        s16x8 af[2];
        #pragma unroll
        for (int mt = 0; mt < 2; ++mt) {
            s16x8 raw = *(const s16x8*)(Vb + (size_t)(w * 2 + mt) * 4096 +
                                        kt * 512 + quad * 128 + cL * 8);
            #pragma unroll
            for (int j = 0; j < 8; ++j)
                af[mt][j] = (short)f2b(b2f((u16)raw[j]) * vidv[j]);
        }
        #pragma unroll
        for (int nt = 0; nt < 4; ++nt) {
            s16x8 bv = *(const s16x8*)(&KtL[nt * 16 + cL][kt * 32 + quad * 8]);
            #pragma unroll
            for (int mt = 0; mt < 2; ++mt) acc[mt][nt] = MFMA16(af[mt], bv, acc[mt][nt]);
        }
    }
    float* out = kvT + ((size_t)((b * 32 + n) * 8 + h)) * 8192;
    #pragma unroll
    for (int mt = 0; mt < 2; ++mt)
        #pragma unroll
        for (int nt = 0; nt < 4; ++nt)
            #pragma unroll
            for (int i = 0; i < 4; ++i)
                out[(w * 32 + mt * 16 + quad * 4 + i) * 64 + nt * 16 + cL] = acc[mt][nt][i];
}

// ---------------------------------------------------------------------------
// PARALLEL scan with register double-buffer prefetch.
// ---------------------------------------------------------------------------
__global__ __launch_bounds__(256) void scan_par(const float* __restrict__ kvT,
                                                u16* __restrict__ kvrecb,
                                                const float* __restrict__ cdv,
                                                float* __restrict__ cscale) {
    int bid = blockIdx.x;
    int n = bid & 31; bid >>= 5;
    int h = bid & 7; int b = bid >> 3;
    int tid = threadIdx.x, lane = tid & 63, g = tid >> 6;
    float cd = cdv[h];
    float st[32], cur[32], nxt[32];
    #pragma unroll
    for (int i = 0; i < 32; ++i) { st[i] = 0.f; nxt[i] = 0.f; }
    if (n > 0) {
        size_t base0 = ((size_t)((b * 32) * 8 + h)) * 8192;
        #pragma unroll
        for (int i = 0; i < 32; ++i) cur[i] = kvT[base0 + (g + 4 * i) * 64 + lane];
    }
    for (int j = 0; j < n; ++j) {
        if (j + 1 < n) {
            size_t basen = ((size_t)((b * 32 + j + 1) * 8 + h)) * 8192;
            #pragma unroll
            for (int i = 0; i < 32; ++i) nxt[i] = kvT[basen + (g + 4 * i) * 64 + lane];
        }
        #pragma unroll
        for (int i = 0; i < 32; ++i) st[i] = st[i] * cd + cur[i];
        #pragma unroll
        for (int i = 0; i < 32; ++i) cur[i] = nxt[i];
    }
    __shared__ float esum[128];
    __shared__ float sSc;
    #pragma unroll
    for (int i = 0; i < 32; ++i) {
        float s = fabsf(st[i]);
        s += __shfl_xor(s, 1, 64);
        s += __shfl_xor(s, 2, 64);
        s += __shfl_xor(s, 4, 64);
        s += __shfl_xor(s, 8, 64);
        s += __shfl_xor(s, 16, 64);
        s += __shfl_xor(s, 32, 64);
        if (lane == 0) esum[g + 4 * i] = s;
    }
    __syncthreads();
    if (tid < 64) {
        float m1 = fmaxf(esum[tid], esum[tid + 64]);
        m1 = fmaxf(m1, __shfl_xor(m1, 1, 64));
        m1 = fmaxf(m1, __shfl_xor(m1, 2, 64));
        m1 = fmaxf(m1, __shfl_xor(m1, 4, 64));
        m1 = fmaxf(m1, __shfl_xor(m1, 8, 64));
        m1 = fmaxf(m1, __shfl_xor(m1, 16, 64));
        m1 = fmaxf(m1, __shfl_xor(m1, 32, 64));
        if (tid == 0) sSc = fmaxf(m1, 1.f);
    }
    __syncthreads();
    float scale = sSc;
    float inv = 1.f / scale;
    size_t baseN = ((size_t)((b * 32 + n) * 8 + h)) * 8192;
    #pragma unroll
    for (int i = 0; i < 32; ++i) {
        int e = g + 4 * i;
        kvrecb[baseN + ((size_t)(lane >> 3) * 128 + e) * 8 + (lane & 7)] = f2b(st[i] * inv);
    }
    if (tid == 0) cscale[(b * 32 + n) * 8 + h] = scale;
}

// ---------------------------------------------------------------------------
// PER-HEAD RMS norm (HD=128) + SiLU gate, in place over g.
// One block per 16-row fpk TILE of g (16 x 1024 = 32KB), grid 2048.
// ---------------------------------------------------------------------------
__global__ __launch_bounds__(256) void rms_silu(const u16* __restrict__ ATT,
                                                u16* __restrict__ g) {
    __shared__ u16 att_s[16 * 1036];
    __shared__ float rmsv[16][8];
    int tile = blockIdx.x;
    int tid = threadIdx.x;
    size_t abase = (size_t)tile * 16 * 1024;
    int head = tid >> 5;
    #pragma unroll
    for (int jj = 0; jj < 16; ++jj) {
        ushort4 v = *(const ushort4*)(ATT + abase + (size_t)jj * 1024 + tid * 4);
        *(ushort4*)(att_s + jj * 1036 + tid * 4) = v;
        float x0 = b2f(v.x), x1 = b2f(v.y), x2 = b2f(v.z), x3 = b2f(v.w);
        float ss = x0 * x0 + x1 * x1 + x2 * x2 + x3 * x3;
        ss += __shfl_xor(ss, 1, 32);
        ss += __shfl_xor(ss, 2, 32);
        ss += __shfl_xor(ss, 4, 32);
        ss += __shfl_xor(ss, 8, 32);
        ss += __shfl_xor(ss, 16, 32);
        if ((tid & 31) == 0)
            rmsv[jj][head] = rsqrtf(ss * (1.f / 128.f) + 1e-6f);
    }
    __syncthreads();
    size_t gbase = (size_t)tile * 16384;
    #pragma unroll
    for (int it = 0; it < 16; ++it) {
        int p = it * 1024 + tid * 4;
        int e = ((p >> 9) << 5) | (((p >> 7) & 3) << 3) | (p & 7);
        int r = (p >> 3) & 15;
        ushort4 gv = *(const ushort4*)(g + gbase + p);
        ushort4 av = *(const ushort4*)(att_s + r * 1036 + e);
        float rms = rmsv[r][e >> 7];
        float x0 = b2f(av.x), x1 = b2f(av.y), x2 = b2f(av.z), x3 = b2f(av.w);
        float g0 = b2f(gv.x), g1 = b2f(gv.y), g2 = b2f(gv.z), g3 = b2f(gv.w);
        ushort4 ov;
        ov.x = f2b((g0 / (1.f + __expf(-g0))) * x0 * rms);
        ov.y = f2b((g1 / (1.f + __expf(-g1))) * x1 * rms);
        ov.z = f2b((g2 / (1.f + __expf(-g2))) * x2 * rms);
        ov.w = f2b((g3 / (1.f + __expf(-g3))) * x3 * rms);
        *(ushort4*)(g + gbase + p) = ov;
    }
}

// ---------------------------------------------------------------------------
extern "C" void kernel_launch(void* const* d_in, const int* in_sizes, int n_in,
                              void* d_out, int out_size, void* d_ws, size_t ws_size,
                              hipStream_t stream) {
    const float* x    = (const float*)d_in[0];
    const float* sn   = (const float*)d_in[1];
    const float* cs   = (const float*)d_in[2];
    const float* mask = (const float*)d_in[3];
    const float* cdv  = (const float*)d_in[4];
    const float* qid  = (const float*)d_in[5];
    const float* vid  = (const float*)d_in[6];
    const float* Wq   = (const float*)d_in[7];
    const float* Wk   = (const float*)d_in[8];
    const float* Wv   = (const float*)d_in[9];
    const float* Wg   = (const float*)d_in[10];
    const float* Wo   = (const float*)d_in[11];
    float* out = (float*)d_out;

    char* w = (char*)d_ws;
    u16* qr     = (u16*)w;   w += (size_t)16777216 * 2;
    u16* kr     = (u16*)w;   w += (size_t)16777216 * 2;
    u16* vt     = (u16*)w;   w += (size_t)33554432 * 2;
    u16* xbf    = (u16*)w;   w += (size_t)16777216 * 2;
    u16* wqT    = (u16*)w;   w += (size_t)262144 * 2;   // contiguous: wq|wk|wv
    u16* wkT    = (u16*)w;   w += (size_t)262144 * 2;
    u16* wvT    = (u16*)w;   w += (size_t)524288 * 2;
    u16* wgT    = (u16*)w;   w += (size_t)524288 * 2;
    u16* woT    = (u16*)w;   w += (size_t)524288 * 2;
    float* kvT  = (float*)w; w += (size_t)8388608 * 4;
    u16* kvrecb = (u16*)w;   w += (size_t)8388608 * 2;
    float* cscale = (float*)w; w += (size_t)1024 * 4;
    u16* maskb  = (u16*)w;   w += (size_t)524288 * 2;

    u16* gbuf = qr;            // 67 MB over dead qr+kr after attn_cross
    u16* ATT  = (u16*)d_out;   // 67 MB bf16 scratch inside the output buffer

    dim3 blk(256);
    cast_x_k<<<dim3(16384), blk, 0, stream>>>(x, xbf);
    cast_mask_k<<<dim3(512), blk, 0, stream>>>(mask, maskb);
    castT_k<<<dim3(16, 16), blk, 0, stream>>>(Wq, wqT, 512, 512, 1.0f);
    castT_k<<<dim3(16, 16), blk, 0, stream>>>(Wk, wkT, 512, 512, 0.125f);
    castT_k<<<dim3(32, 16), blk, 0, stream>>>(Wv, wvT, 512, 1024, 1.0f);
    castT_k<<<dim3(32, 16), blk, 0, stream>>>(Wg, wgT, 512, 1024, 1.0f);
    castT_k<<<dim3(16, 32), blk, 0, stream>>>(Wo, woT, 1024, 512, 1.0f);
    // merged q|k|v projection (wqT/wkT/wvT contiguous -> N=2048)
    gemm_proj<<<dim3(16, 256), blk, 0, stream>>>(xbf, wqT, qr, kr, vt, sn, cs);
    // retention state chain first (kr/vt only), then fused attn+cross
    chunkkv_mfma<<<dim3(1024), blk, 0, stream>>>(kr, vt, vid, kvT);
    scan_par<<<dim3(1024), blk, 0, stream>>>(kvT, kvrecb, cdv, cscale);
    attn_cross<<<dim3(4096), blk, 0, stream>>>(qr, kr, vt, maskb, kvrecb, cscale,
                                               qid, ATT);
    gemm_mfma<2><<<dim3(8, 256), blk, 0, stream>>>(xbf, wgT, gbuf, 512, 1024);
    rms_silu<<<dim3(2048), blk, 0, stream>>>(ATT, gbuf);
    gemm_mfma<3><<<dim3(4, 256), blk, 0, stream>>>(gbuf, woT, out, 1024, 512);
}